// Round 7
// baseline (219.487 us; speedup 1.0000x reference)
//
#include <hip/hip_runtime.h>
#include <hip/hip_bf16.h>
#include <stdint.h>

#define B_   64
#define L_   4096
#define H_   128
#define HG_  16            // h-channels per block
#define NG_  8             // h-groups -> 512 blocks
#define TI_  128           // timesteps per iteration
#define NIT_ 32            // iterations (L/TI)
#define LOG2E 1.44269504088896340736f

// s_ab / s_y: row stride 17 u32, h-index xor'd by (t>>2)&15 -> low-conflict
#define ABI(t,h) ((t)*17 + ((h) ^ (((t)>>2) & 15)))

typedef __attribute__((ext_vector_type(8))) short short8;
typedef __attribute__((ext_vector_type(4))) float floatx4;

__device__ __forceinline__ unsigned short f2bf(float f){
    unsigned int u = __float_as_uint(f);
    u += 0x7FFFu + ((u >> 16) & 1u);      // RNE
    return (unsigned short)(u >> 16);
}

// K1: inp = x @ Wp + bp -> bf16 [t][128], coalesced. Pure memory-bound.
// One thread per (t, 8h-chunk): 4M threads.
__global__ __launch_bounds__(1024)
void inp_proj(const float* __restrict__ x, const float* __restrict__ Wp,
              const float* __restrict__ bp, unsigned short* __restrict__ inp_g)
{
    const int tid = threadIdx.x;
    const int h0 = (tid & 15) * 8;
    const size_t id = (size_t)blockIdx.x*1024 + tid;    // 0 .. 4194303
    const size_t t = id >> 4;
    const float* xr = x + t*3;
    const float x0 = xr[0], x1 = xr[1], x2 = xr[2];
    floatx4 wa0 = *(const floatx4*)&Wp[h0],      wb0 = *(const floatx4*)&Wp[h0+4];
    floatx4 wa1 = *(const floatx4*)&Wp[H_+h0],   wb1 = *(const floatx4*)&Wp[H_+h0+4];
    floatx4 wa2 = *(const floatx4*)&Wp[2*H_+h0], wb2 = *(const floatx4*)&Wp[2*H_+h0+4];
    floatx4 ba  = *(const floatx4*)&bp[h0],      bb4 = *(const floatx4*)&bp[h0+4];
    short8 pk;
    #pragma unroll
    for (int m = 0; m < 4; ++m){
        float v = fmaf(x2, wa2[m], fmaf(x1, wa1[m], fmaf(x0, wa0[m], ba[m])));
        pk[m] = (short)f2bf(v);
        float w = fmaf(x2, wb2[m], fmaf(x1, wb1[m], fmaf(x0, wb0[m], bb4[m])));
        pk[4+m] = (short)f2bf(w);
    }
    *(short8*)&inp_g[t*H_ + h0] = pk;
}

// K2: fused recurrence. 512 blocks x 1024 threads. Block (bb,g): bb = bid&63,
// g = bid>>6 -> the 8 groups of a batch row land on the same XCD (64 % 8 == 0),
// so their reads of the same inp tile are L2 hits. Register carry h_run.
// Per iter (2 barriers):
//   B: MFMA (wave = (gate, t-tile)) + gate epilogue -> s_ab
//   BAR_A
//   issue next inp tile loads (global->reg) | C: 2-step local scan + 64-wide
//   Kogge + replay -> s_y | ds_write staged tile -> s_inp
//   BAR_B
//   D: y-reduce over 16 h + store partials   (flows into next B)
// Global source is chunk-permuted at read time (c ^ (t&15), involution) so LDS
// stays LINEAR (coalesced stage) while MFMA A-frag reads spread 8 words/bank.
__global__ __launch_bounds__(1024, 4)
void fused_rnn(const unsigned short* __restrict__ inp_g,
               const float* __restrict__ Wz, const float* __restrict__ bz,
               const float* __restrict__ Wh, const float* __restrict__ bh,
               const float* __restrict__ Wg,
               float* __restrict__ partials)
{
    __shared__ __align__(16) unsigned short s_inp[TI_*H_];   // 32768 B (weights stage here first)
    __shared__ unsigned int s_ab[TI_*17];                    // 8704 B (a,th) bf16 pairs
    __shared__ float s_y[TI_*17];                            // 8704 B
    // total 50176 B -> 2 blocks/CU possible

    const int bid = blockIdx.x;
    const int bb  = bid & 63;
    const int g   = bid >> 6;
    const int tid = threadIdx.x;
    const int wv = tid >> 6, lane = tid & 63, quad = lane >> 4, l15 = lane & 15;
    const int G = wv >> 3, tile = wv & 7;     // wave role: gate G, t-tile

    // ---- weight staging: Wz/Wh -> bf16 [gate][n][k] at s_inp (transient) ----
    {
        const float* Wsrc = (tid >= 512) ? Wh : Wz;
        const int r  = tid & 511;
        const int n  = r >> 5;                // 0..15
        const int k0 = (r & 31) * 4;          // 0..124
        unsigned short* dst = s_inp + (tid >> 9)*2048 + n*H_ + k0;
        const float* src = Wsrc + (size_t)k0*H_ + g*HG_ + n;
        #pragma unroll
        for (int j = 0; j < 4; ++j)
            dst[j] = f2bf(src[(size_t)j*H_]);
    }
    __syncthreads();

    short8 bfr[4];                            // this wave's gate B-frags (16 VGPR)
    #pragma unroll
    for (int kk = 0; kk < 4; ++kk)
        bfr[kk] = *(const short8*)&s_inp[G*2048 + l15*H_ + kk*32 + quad*8];
    const float biasv = (G ? bh : bz)[g*HG_ + l15];
    const float wgv   = Wg[g*HG_ + wv];       // wave wv owns h-channel wv in C

    // ---- stage addressing (iteration-invariant) ----
    // LDS linear 16B-chunk p = k*1024 + tid: t = p>>4, cl = p&15.
    // global chunk for that slot = cl ^ (t&15)  (involution).
    const int t0 = tid >> 4, cl = tid & 15;
    const char* gsrc = (const char*)(inp_g + (size_t)bb*L_*H_)
                     + (size_t)t0*256 + (size_t)((cl ^ (t0 & 15)) << 4);
    // second chunk: t0+64 -> (t0+64)&15 == t0&15 -> just +16384 bytes
    char* ldst = (char*)s_inp + tid*16;

    // ---- prologue: stage tile 0 ----
    floatx4 ld0 = *(const floatx4*)gsrc;
    floatx4 ld1 = *(const floatx4*)(gsrc + 16384);
    __syncthreads();                          // all bfr reads done before overwrite
    *(floatx4*)ldst           = ld0;
    *(floatx4*)(ldst + 16384) = ld1;
    __syncthreads();                          // s_inp tile 0 ready

    float h_run = 0.0f;
    float* pbase = partials + ((size_t)(g*B_ + bb))*L_;

    // A-frag read base: data chunk kk*4+quad of row t sits at lds chunk
    // (kk*4+quad)^l15 = ((kk^kx)<<2) | (quad^(l15&3)). The read at byte
    // offset ((kk^kx)<<6) therefore yields K-slice kk's data -> pair with
    // bfr[kk]. (R6 bug: pairing with bfr[kk^kx] mismatched frags for l15>=4.)
    const char* abase = (const char*)s_inp + (tile*16 + l15)*256
                      + ((quad ^ (l15 & 3)) << 4);
    const int kx = (l15 >> 2) & 3;

    #pragma unroll 1
    for (int it = 0; it < NIT_; ++it){
        // ---- phase B: MFMA (one gate, one t-tile) + epilogue -> s_ab ----
        {
            floatx4 acc = (floatx4){0.f,0.f,0.f,0.f};
            #pragma unroll
            for (int kk = 0; kk < 4; ++kk){
                short8 af = *(const short8*)(abase + ((kk ^ kx) << 6));
                acc = __builtin_amdgcn_mfma_f32_16x16x32_bf16(af, bfr[kk], acc, 0, 0, 0);
            }
            #pragma unroll
            for (int e = 0; e < 4; ++e){
                int t = tile*16 + quad*4 + e;
                float v = acc[e] + biasv;
                float r;
                if (G == 0){
                    r = __builtin_amdgcn_rcpf(1.0f + __builtin_amdgcn_exp2f(v * LOG2E)); // a = 1-z
                } else {
                    float ex = __builtin_amdgcn_exp2f(2.0f*LOG2E*v);
                    r = 1.0f - 2.0f*__builtin_amdgcn_rcpf(ex + 1.0f);                    // tanh
                }
                ((unsigned short*)s_ab)[ABI(t, l15)*2 + G] = f2bf(r);
            }
        }
        __syncthreads();   // BAR_A: s_ab ready; s_inp reads done

        // ---- issue next-tile loads (latency hidden under C) ----
        floatx4 nld0, nld1;
        const bool more = (it + 1 < NIT_);
        if (more){
            const char* gs = gsrc + (size_t)(it+1)*32768;
            nld0 = *(const floatx4*)gs;
            nld1 = *(const floatx4*)(gs + 16384);
        }

        // ---- phase C: wave wv = channel wv; lane = 2-t segment; Kogge(64) ----
        {
            int t = lane*2;
            unsigned int u0 = s_ab[ABI(t,   wv)];
            unsigned int u1 = s_ab[ABI(t+1, wv)];
            float a0  = __uint_as_float(u0 << 16);
            float th0 = __uint_as_float(u0 & 0xffff0000u);
            float b0  = fmaf(-a0, th0, th0);
            float a1  = __uint_as_float(u1 << 16);
            float th1 = __uint_as_float(u1 & 0xffff0000u);
            float b1  = fmaf(-a1, th1, th1);
            float P = a0 * a1;
            float Q = fmaf(a1, b0, b1);
            #pragma unroll
            for (int d = 1; d < 64; d <<= 1){
                float pP = __shfl_up(P, d, 64);
                float pQ = __shfl_up(Q, d, 64);
                if (lane >= d){
                    Q = fmaf(P, pQ, Q);
                    P = P * pP;
                }
            }
            float eP = __shfl_up(P, 1, 64);
            float eQ = __shfl_up(Q, 1, 64);
            if (lane == 0){ eP = 1.0f; eQ = 0.0f; }
            float tP = __shfl(P, 63, 64);
            float tQ = __shfl(Q, 63, 64);
            float hh = fmaf(eP, h_run, eQ);          // h_{t-1} at segment entry
            h_run = fmaf(tP, h_run, tQ);             // carry to next iteration
            s_y[ABI(t, wv)] = wgv * hh;
            hh = fmaf(a0, hh, b0);
            s_y[ABI(t+1, wv)] = wgv * hh;
        }

        // ---- write staged tile (vmcnt drains here, after C covered latency) ----
        if (more){
            *(floatx4*)ldst           = nld0;
            *(floatx4*)(ldst + 16384) = nld1;
        }
        __syncthreads();   // BAR_B: s_y + next s_inp ready

        // ---- phase D: y-reduce over 16 h; store; flows into next B ----
        {
            int dt = tid >> 3, dp = tid & 7;
            float s = s_y[ABI(dt, dp*2)] + s_y[ABI(dt, dp*2 + 1)];
            s += __shfl_xor(s, 1, 64);
            s += __shfl_xor(s, 2, 64);
            s += __shfl_xor(s, 4, 64);
            if (dp == 0)
                pbase[it*TI_ + dt] = s;
        }
    }
}

// K3: preds = bg + sum of 8 group partials (float4). 64 blocks x 1024.
__global__ __launch_bounds__(1024)
void gather(const floatx4* __restrict__ partials, const float* __restrict__ bg,
            floatx4* __restrict__ preds)
{
    size_t i = (size_t)blockIdx.x*1024 + threadIdx.x;       // 0 .. 65535
    const size_t S = (size_t)B_ * L_ / 4;                   // 65536
    float b = bg[0];
    floatx4 v = partials[i];
    #pragma unroll
    for (int gg = 1; gg < NG_; ++gg) v += partials[gg*S + i];
    v[0] += b; v[1] += b; v[2] += b; v[3] += b;
    preds[i] = v;
}

extern "C" void kernel_launch(void* const* d_in, const int* in_sizes, int n_in,
                              void* d_out, int out_size, void* d_ws, size_t ws_size,
                              hipStream_t stream){
    const float* x  = (const float*)d_in[0];
    const float* Wp = (const float*)d_in[1];
    const float* bp = (const float*)d_in[2];
    const float* Wz = (const float*)d_in[3];
    const float* bz = (const float*)d_in[4];
    const float* Wh = (const float*)d_in[5];
    const float* bh = (const float*)d_in[6];
    const float* Wg = (const float*)d_in[7];
    const float* bg = (const float*)d_in[8];
    float* preds = (float*)d_out;

    uint8_t* w8 = (uint8_t*)d_ws;
    unsigned short* inp_g = (unsigned short*)w8;            // 64 MB bf16 [t][128]
    float* partials = (float*)(w8 + 67108864);              // 8 MB [g][bb][l]

    hipLaunchKernelGGL(inp_proj, dim3(4096), dim3(1024), 0, stream, x, Wp, bp, inp_g);
    hipLaunchKernelGGL(fused_rnn, dim3(B_*NG_), dim3(1024), 0, stream,
                       inp_g, Wz, bz, Wh, bh, Wg, partials);
    hipLaunchKernelGGL(gather, dim3(B_*L_/4096), dim3(1024), 0, stream,
                       (const floatx4*)partials, bg, (floatx4*)preds);
}

// Round 8
// 193.448 us; speedup vs baseline: 1.1346x; 1.1346x over previous
//
#include <hip/hip_runtime.h>
#include <hip/hip_bf16.h>
#include <stdint.h>

#define B_   64
#define L_   4096
#define H_   128
#define HG_  32            // h-channels per block
#define NG_  4             // h-groups -> 256 blocks, exactly 1/CU
#define TI_  256           // timesteps per iteration
#define NIT_ 16            // iterations (L/TI)
#define CSTR 260           // col stride (u32) for s_ab / s_y
#define LOG2E 1.44269504088896340736f

typedef __attribute__((ext_vector_type(8))) short short8;
typedef __attribute__((ext_vector_type(4))) float floatx4;
typedef __attribute__((ext_vector_type(4))) unsigned int uintx4;

__device__ __forceinline__ unsigned short f2bf(float f){
    unsigned int u = __float_as_uint(f);
    u += 0x7FFFu + ((u >> 16) & 1u);      // RNE
    return (unsigned short)(u >> 16);
}

// K1: inp = x @ Wp + bp -> bf16 [t][128], coalesced. Memory-bound. (verified R7)
__global__ __launch_bounds__(1024)
void inp_proj(const float* __restrict__ x, const float* __restrict__ Wp,
              const float* __restrict__ bp, unsigned short* __restrict__ inp_g)
{
    const int tid = threadIdx.x;
    const int h0 = (tid & 15) * 8;
    const size_t id = (size_t)blockIdx.x*1024 + tid;    // 0 .. 4194303
    const size_t t = id >> 4;
    const float* xr = x + t*3;
    const float x0 = xr[0], x1 = xr[1], x2 = xr[2];
    floatx4 wa0 = *(const floatx4*)&Wp[h0],      wb0 = *(const floatx4*)&Wp[h0+4];
    floatx4 wa1 = *(const floatx4*)&Wp[H_+h0],   wb1 = *(const floatx4*)&Wp[H_+h0+4];
    floatx4 wa2 = *(const floatx4*)&Wp[2*H_+h0], wb2 = *(const floatx4*)&Wp[2*H_+h0+4];
    floatx4 ba  = *(const floatx4*)&bp[h0],      bb4 = *(const floatx4*)&bp[h0+4];
    short8 pk;
    #pragma unroll
    for (int m = 0; m < 4; ++m){
        float v = fmaf(x2, wa2[m], fmaf(x1, wa1[m], fmaf(x0, wa0[m], ba[m])));
        pk[m] = (short)f2bf(v);
        float w = fmaf(x2, wb2[m], fmaf(x1, wb1[m], fmaf(x0, wb0[m], bb4[m])));
        pk[4+m] = (short)f2bf(w);
    }
    *(short8*)&inp_g[t*H_ + h0] = pk;
}

// K2: fused recurrence. 256 blocks x 1024 threads, exactly 1 block/CU.
// Block (bb,g): bb = bid&63, g = bid>>6 (same-XCD inp sharing: 64 % 8 == 0).
// TI=256 per iteration, NIT=16. Per iter (2 barriers):
//   B: issue next-tile global loads FIRST (latency covered by whole phase),
//      then MFMA (wave = (gate, n-half, t-quarter), 4 tiles) + epilogue -> s_ab
//   BAR_A; ds_write staged tile (vmcnt drains, covered by B)
//   C: per-wave 2 channels: 4-t local scan + interleaved 64-wide Kogge +
//      replay -> s_y (b128 LDS, conflict-free via t ^ ((col&7)<<2) swizzle)
//   BAR_B
//   D: y-reduce over 32 cols + store partials (flows into next B)
__global__ __launch_bounds__(1024, 4)
void fused_rnn(const unsigned short* __restrict__ inp_g,
               const float* __restrict__ Wz, const float* __restrict__ bz,
               const float* __restrict__ Wh, const float* __restrict__ bh,
               const float* __restrict__ Wg,
               float* __restrict__ partials)
{
    __shared__ __align__(16) unsigned short s_inp[TI_*H_];   // 65536 B (weights stage here first)
    __shared__ __align__(16) unsigned int  s_ab[HG_*CSTR];   // 33280 B (a,th) bf16 pairs, col-major
    __shared__ __align__(16) float         s_y[HG_*CSTR];    // 33280 B
    // total 132096 B -> 1 block/CU

    const int bid = blockIdx.x;
    const int bb  = bid & 63;
    const int g   = bid >> 6;
    const int tid = threadIdx.x;
    const int wv = tid >> 6, lane = tid & 63, quad = lane >> 4, l15 = lane & 15;
    const int G  = wv >> 3;           // gate
    const int nh = (wv >> 2) & 1;     // n-half (16 cols)
    const int tb = wv & 3;            // t-quarter base: tiles tb, tb+4, tb+8, tb+12

    // ---- weight staging: Wz/Wh -> bf16 [gate][n(32)][k(128)] in s_inp ----
    {
        const float* Wsrc = (tid >= 512) ? Wh : Wz;
        const int r  = tid & 511;
        const int n  = r >> 4;                // 0..31
        const int k0 = (r & 15) * 8;          // 0..120
        unsigned short* dst = s_inp + (tid >> 9)*4096 + n*H_ + k0;
        const float* src = Wsrc + (size_t)k0*H_ + g*HG_ + n;
        #pragma unroll
        for (int j = 0; j < 8; ++j)
            dst[j] = f2bf(src[(size_t)j*H_]);
    }
    __syncthreads();

    short8 bfr[4];                            // this wave's (gate, n-half) B-frags
    #pragma unroll
    for (int kk = 0; kk < 4; ++kk)
        bfr[kk] = *(const short8*)&s_inp[G*4096 + (nh*16 + l15)*H_ + kk*32 + quad*8];
    const float biasv = (G ? bh : bz)[g*HG_ + nh*16 + l15];
    const float wg0 = Wg[g*HG_ + wv];         // C-phase channel wv
    const float wg1 = Wg[g*HG_ + wv + 16];    // and wv+16

    // ---- stage addressing (verified R7 algebra): LDS linear, global chunk-permuted ----
    const int t0 = tid >> 4, cl = tid & 15;
    const char* gsrc = (const char*)(inp_g + (size_t)bb*L_*H_)
                     + (size_t)t0*256 + (size_t)((cl ^ (t0 & 15)) << 4);
    char* ldst = (char*)s_inp + tid*16;

    // ---- prologue: stage tile 0 (4 x 16KB quarters; (t0+64j)&15 == t0&15) ----
    floatx4 ld0 = *(const floatx4*)gsrc;
    floatx4 ld1 = *(const floatx4*)(gsrc + 16384);
    floatx4 ld2 = *(const floatx4*)(gsrc + 32768);
    floatx4 ld3 = *(const floatx4*)(gsrc + 49152);
    __syncthreads();                          // bfr reads done before overwrite
    *(floatx4*)ldst           = ld0;
    *(floatx4*)(ldst + 16384) = ld1;
    *(floatx4*)(ldst + 32768) = ld2;
    *(floatx4*)(ldst + 49152) = ld3;
    __syncthreads();                          // tile 0 ready

    // A-frag base (verified R6/R7): data chunk kk*4+quad of row t at lds chunk
    // (kk*4+quad)^l15; read at +((kk^kx)<<6) pairs with bfr[kk].
    const char* abase = (const char*)s_inp + (tb*16 + l15)*256
                      + ((quad ^ (l15 & 3)) << 4);
    const int kx = (l15 >> 2) & 3;

    float h_run0 = 0.0f, h_run1 = 0.0f;
    float* pbase = partials + ((size_t)(g*B_ + bb))*L_;

    #pragma unroll 1
    for (int it = 0; it < NIT_; ++it){
        const bool more = (it + 1 < NIT_);
        // ---- issue next-tile loads FIRST: latency covered by whole B phase ----
        if (more){
            const char* gs = gsrc + (size_t)(it+1)*65536;
            ld0 = *(const floatx4*)gs;
            ld1 = *(const floatx4*)(gs + 16384);
            ld2 = *(const floatx4*)(gs + 32768);
            ld3 = *(const floatx4*)(gs + 49152);
        }

        // ---- phase B: 4 MFMA tiles + epilogue -> s_ab ----
        {
            floatx4 acc[4];
            #pragma unroll
            for (int u = 0; u < 4; ++u) acc[u] = (floatx4){0.f,0.f,0.f,0.f};
            #pragma unroll
            for (int u = 0; u < 4; ++u)
                #pragma unroll
                for (int kk = 0; kk < 4; ++kk){
                    short8 af = *(const short8*)(abase + u*16384 + ((kk ^ kx) << 6));
                    acc[u] = __builtin_amdgcn_mfma_f32_16x16x32_bf16(af, bfr[kk], acc[u], 0, 0, 0);
                }
            const int col = nh*16 + l15;
            const int tswz = (col & 7) << 2;
            #pragma unroll
            for (int u = 0; u < 4; ++u)
                #pragma unroll
                for (int e = 0; e < 4; ++e){
                    int t = (tb + 4*u)*16 + quad*4 + e;
                    float v = acc[u][e] + biasv;
                    float r;
                    if (G == 0){
                        r = __builtin_amdgcn_rcpf(1.0f + __builtin_amdgcn_exp2f(v * LOG2E)); // a = 1-z
                    } else {
                        float ex = __builtin_amdgcn_exp2f(2.0f*LOG2E*v);
                        r = 1.0f - 2.0f*__builtin_amdgcn_rcpf(ex + 1.0f);                    // tanh
                    }
                    ((unsigned short*)s_ab)[(col*CSTR + (t ^ tswz))*2 + G] = f2bf(r);
                }
        }
        __syncthreads();   // BAR_A: s_ab ready; s_inp reads done

        // ---- write staged tile (vmcnt drains here; loads issued a phase ago) ----
        if (more){
            *(floatx4*)ldst           = ld0;
            *(floatx4*)(ldst + 16384) = ld1;
            *(floatx4*)(ldst + 32768) = ld2;
            *(floatx4*)(ldst + 49152) = ld3;
        }

        // ---- phase C: wave wv = channels {wv, wv+16}; lane = 4-t segment;
        //      two interleaved Kogge(64) chains hide each other's shfl latency ----
        {
            const int c0 = wv, c1 = wv + 16;
            const int i0 = c0*CSTR + ((lane*4) ^ ((c0 & 7) << 2));
            const int i1 = c1*CSTR + ((lane*4) ^ ((c1 & 7) << 2));
            uintx4 ua = *(const uintx4*)&s_ab[i0];
            uintx4 ub = *(const uintx4*)&s_ab[i1];
            float a0[4], b0v[4], a1[4], b1v[4];
            float P0 = 1.0f, Q0 = 0.0f, P1 = 1.0f, Q1 = 0.0f;
            #pragma unroll
            for (int j = 0; j < 4; ++j){
                float a  = __uint_as_float(ua[j] << 16);
                float th = __uint_as_float(ua[j] & 0xffff0000u);
                float b  = fmaf(-a, th, th);
                a0[j] = a; b0v[j] = b;
                Q0 = fmaf(a, Q0, b); P0 *= a;
                float c  = __uint_as_float(ub[j] << 16);
                float td = __uint_as_float(ub[j] & 0xffff0000u);
                float d  = fmaf(-c, td, td);
                a1[j] = c; b1v[j] = d;
                Q1 = fmaf(c, Q1, d); P1 *= c;
            }
            #pragma unroll
            for (int d = 1; d < 64; d <<= 1){
                float pP0 = __shfl_up(P0, d, 64);
                float pQ0 = __shfl_up(Q0, d, 64);
                float pP1 = __shfl_up(P1, d, 64);
                float pQ1 = __shfl_up(Q1, d, 64);
                if (lane >= d){
                    Q0 = fmaf(P0, pQ0, Q0); P0 *= pP0;
                    Q1 = fmaf(P1, pQ1, Q1); P1 *= pP1;
                }
            }
            float eP0 = __shfl_up(P0, 1, 64), eQ0 = __shfl_up(Q0, 1, 64);
            float eP1 = __shfl_up(P1, 1, 64), eQ1 = __shfl_up(Q1, 1, 64);
            if (lane == 0){ eP0 = 1.0f; eQ0 = 0.0f; eP1 = 1.0f; eQ1 = 0.0f; }
            float tP0 = __shfl(P0, 63, 64), tQ0 = __shfl(Q0, 63, 64);
            float tP1 = __shfl(P1, 63, 64), tQ1 = __shfl(Q1, 63, 64);
            float hh0 = fmaf(eP0, h_run0, eQ0);      // h_{t-1} at segment entry
            float hh1 = fmaf(eP1, h_run1, eQ1);
            h_run0 = fmaf(tP0, h_run0, tQ0);         // carry to next iteration
            h_run1 = fmaf(tP1, h_run1, tQ1);
            floatx4 y0v, y1v;
            #pragma unroll
            for (int j = 0; j < 4; ++j){
                y0v[j] = wg0 * hh0; hh0 = fmaf(a0[j], hh0, b0v[j]);
                y1v[j] = wg1 * hh1; hh1 = fmaf(a1[j], hh1, b1v[j]);
            }
            *(floatx4*)&s_y[i0] = y0v;
            *(floatx4*)&s_y[i1] = y1v;
        }
        __syncthreads();   // BAR_B: s_y ready; next s_inp tile ready

        // ---- phase D: y-reduce over 32 cols; store; flows into next B ----
        {
            const int dt = tid >> 2, dp = tid & 3;
            float s = 0.0f;
            #pragma unroll
            for (int i = 0; i < 8; ++i){
                int c = dp*8 + i;
                s += s_y[c*CSTR + (dt ^ ((c & 7) << 2))];
            }
            s += __shfl_xor(s, 1, 64);
            s += __shfl_xor(s, 2, 64);
            if (dp == 0)
                pbase[it*TI_ + dt] = s;
        }
    }
}

// K3: preds = bg + sum of 4 group partials (float4). 64 blocks x 1024.
__global__ __launch_bounds__(1024)
void gather(const floatx4* __restrict__ partials, const float* __restrict__ bg,
            floatx4* __restrict__ preds)
{
    size_t i = (size_t)blockIdx.x*1024 + threadIdx.x;       // 0 .. 65535
    const size_t S = (size_t)B_ * L_ / 4;                   // 65536
    float b = bg[0];
    floatx4 v = partials[i];
    #pragma unroll
    for (int gg = 1; gg < NG_; ++gg) v += partials[gg*S + i];
    v[0] += b; v[1] += b; v[2] += b; v[3] += b;
    preds[i] = v;
}

extern "C" void kernel_launch(void* const* d_in, const int* in_sizes, int n_in,
                              void* d_out, int out_size, void* d_ws, size_t ws_size,
                              hipStream_t stream){
    const float* x  = (const float*)d_in[0];
    const float* Wp = (const float*)d_in[1];
    const float* bp = (const float*)d_in[2];
    const float* Wz = (const float*)d_in[3];
    const float* bz = (const float*)d_in[4];
    const float* Wh = (const float*)d_in[5];
    const float* bh = (const float*)d_in[6];
    const float* Wg = (const float*)d_in[7];
    const float* bg = (const float*)d_in[8];
    float* preds = (float*)d_out;

    uint8_t* w8 = (uint8_t*)d_ws;
    unsigned short* inp_g = (unsigned short*)w8;            // 64 MB bf16 [t][128] (chunk-permuted)
    float* partials = (float*)(w8 + 67108864);              // 4 MB [g][bb][l]

    hipLaunchKernelGGL(inp_proj, dim3(4096), dim3(1024), 0, stream, x, Wp, bp, inp_g);
    hipLaunchKernelGGL(fused_rnn, dim3(B_*NG_), dim3(1024), 0, stream,
                       inp_g, Wz, bz, Wh, bh, Wg, partials);
    hipLaunchKernelGGL(gather, dim3(B_*L_/4096), dim3(1024), 0, stream,
                       (const floatx4*)partials, bg, (floatx4*)preds);
}